// Round 1
// baseline (329.963 us; speedup 1.0000x reference)
//
#include <hip/hip_runtime.h>
#include <hip/hip_bf16.h>

#define BSZ 4
#define SEQ 512
#define HID 768
#define VOC 30522
#define NPAD 30592   // 239*128

typedef __attribute__((ext_vector_type(8))) short short8;
typedef __attribute__((ext_vector_type(4))) float f32x4;

typedef const unsigned int __attribute__((address_space(1)))* gptr_t;
typedef unsigned int __attribute__((address_space(3)))* lptr_t;

__device__ __forceinline__ void gload_lds16(const void* g, void* l) {
    __builtin_amdgcn_global_load_lds((gptr_t)g, (lptr_t)l, 16, 0, 0);
}

// ---------------- span scans: fw = cummax, bw = reverse cummin ----------------
__global__ __launch_bounds__(512) void scan_kernel(const int* __restrict__ span,
                                                   int* __restrict__ fw, int* __restrict__ bw) {
    int b = blockIdx.x;
    int j = threadIdx.x;   // 0..511
    __shared__ int sm[SEQ];
    __shared__ int sc[SEQ];
    int m = (span[b * SEQ + j] > -1) ? 1 : 0;
    sm[j] = m;
    __syncthreads();
    int prev = (j > 0) ? sm[j - 1] : 0;
    int nxt  = (j < SEQ - 1) ? sm[j + 1] : 0;
    int cfw = (m && !prev && j > 0) ? (j - 1) : 0;
    int cbw = (m && !nxt && j < SEQ - 1) ? (j + 1) : (SEQ - 1);

    // inclusive cummax (forward)
    int v = cfw;
    sc[j] = v; __syncthreads();
    for (int off = 1; off < SEQ; off <<= 1) {
        int o = (j >= off) ? sc[j - off] : 0;
        __syncthreads();
        v = max(v, o);
        sc[j] = v; __syncthreads();
    }
    fw[b * SEQ + j] = v;

    // inclusive reverse cummin
    v = cbw;
    sc[j] = v; __syncthreads();
    for (int off = 1; off < SEQ; off <<= 1) {
        int o = (j + off < SEQ) ? sc[j + off] : (SEQ - 1);
        __syncthreads();
        v = min(v, o);
        sc[j] = v; __syncthreads();
    }
    bw[b * SEQ + j] = v;
}

// ---------------- build X = [fw_h | bw_h | pe] * mask, bf16 ----------------
__global__ __launch_bounds__(256) void build_x(const float* __restrict__ h,
                                               const int* __restrict__ span,
                                               const float* __restrict__ pe,
                                               const int* __restrict__ fw,
                                               const int* __restrict__ bw,
                                               __hip_bfloat16* __restrict__ X) {
    int r = blockIdx.x;            // 0..2047
    int b = r >> 9, s = r & (SEQ - 1);
    float mf = (span[r] > -1) ? 1.f : 0.f;
    int f = fw[r], w = bw[r];
    const float* hf = h + ((size_t)b * SEQ + f) * HID;
    const float* hb = h + ((size_t)b * SEQ + w) * HID;
    const float* pp = pe + (size_t)s * HID;
    __hip_bfloat16* xr = X + (size_t)r * (3 * HID);
    for (int c = threadIdx.x; c < HID; c += 256) {
        xr[c]            = __float2bfloat16(hf[c] * mf);
        xr[HID + c]      = __float2bfloat16(hb[c] * mf);
        xr[2 * HID + c]  = __float2bfloat16(pp[c] * mf);
    }
}

// ---------------- transpose + f32->bf16: Wt[n][k] = W[k][n] ----------------
__global__ __launch_bounds__(256) void transpose_bf16(const float* __restrict__ W,
                                                      __hip_bfloat16* __restrict__ Wt,
                                                      int K, int N) {
    __shared__ float t[32][33];
    int n0 = blockIdx.x * 32, k0 = blockIdx.y * 32;
    int tx = threadIdx.x, ty = threadIdx.y;  // (32,8)
    #pragma unroll
    for (int i = 0; i < 32; i += 8) {
        int k = k0 + ty + i, n = n0 + tx;
        t[ty + i][tx] = (n < N) ? W[(size_t)k * N + n] : 0.f;
    }
    __syncthreads();
    #pragma unroll
    for (int i = 0; i < 32; i += 8) {
        int n = n0 + ty + i, k = k0 + tx;
        Wt[(size_t)n * K + k] = __float2bfloat16(t[tx][ty + i]);
    }
}

// ---------------- bias + exact gelu + layernorm -> bf16 ----------------
__global__ __launch_bounds__(256) void gelu_ln(const float* __restrict__ Y,
                                               const float* __restrict__ bias,
                                               const float* __restrict__ g,
                                               const float* __restrict__ be,
                                               __hip_bfloat16* __restrict__ out) {
    int r = blockIdx.x;
    const float* y = Y + (size_t)r * HID;
    float z[3];
    float s1 = 0.f, s2 = 0.f;
    #pragma unroll
    for (int i = 0; i < 3; i++) {
        int c = threadIdx.x + i * 256;
        float x = y[c] + bias[c];
        float zz = 0.5f * x * (1.f + erff(x * 0.70710678118654752f));
        z[i] = zz; s1 += zz; s2 += zz * zz;
    }
    #pragma unroll
    for (int off = 32; off; off >>= 1) {
        s1 += __shfl_down(s1, off);
        s2 += __shfl_down(s2, off);
    }
    __shared__ float p1[4], p2[4];
    int w = threadIdx.x >> 6, lane = threadIdx.x & 63;
    if (lane == 0) { p1[w] = s1; p2[w] = s2; }
    __syncthreads();
    s1 = p1[0] + p1[1] + p1[2] + p1[3];
    s2 = p2[0] + p2[1] + p2[2] + p2[3];
    float mu = s1 * (1.f / HID);
    float var = s2 * (1.f / HID) - mu * mu;
    float rs = rsqrtf(var + 1e-12f);
    __hip_bfloat16* o = out + (size_t)r * HID;
    #pragma unroll
    for (int i = 0; i < 3; i++) {
        int c = threadIdx.x + i * 256;
        o[c] = __float2bfloat16((z[i] - mu) * rs * g[c] + be[c]);
    }
}

// ---------------- MFMA GEMM: C[M,N] = A[M,K] @ Bt[N,K]^T ----------------
// 128x128 tile, BK=64, 256 threads (4 waves 2x2), 16x16x32 bf16 MFMA.
template<bool BIAS_EDGE>
__global__ __launch_bounds__(256) void gemm_kernel(const __hip_bfloat16* __restrict__ A,
                                                   const __hip_bfloat16* __restrict__ Bt,
                                                   float* __restrict__ C,
                                                   int K, int Nvalid,
                                                   const float* __restrict__ bias, int ldc) {
    __shared__ __hip_bfloat16 As[128 * 64];
    __shared__ __hip_bfloat16 Bs[128 * 64];
    int bx = blockIdx.x;   // N tile
    int by = blockIdx.y;   // M tile
    int t = threadIdx.x;
    int lane = t & 63, w = t >> 6;
    int wm = w >> 1, wn = w & 1;

    const __hip_bfloat16* Ab = A + (size_t)(by * 128) * K;
    const __hip_bfloat16* Bb = Bt + (size_t)(bx * 128) * K;

    f32x4 acc[4][4] = {};

    for (int k0 = 0; k0 < K; k0 += 64) {
        #pragma unroll
        for (int i = 0; i < 4; i++) {
            int c = i * 256 + t;
            int row = c >> 3, col = (c & 7) * 8;
            gload_lds16(Ab + (size_t)row * K + k0 + col, (char*)As + c * 16);
            gload_lds16(Bb + (size_t)row * K + k0 + col, (char*)Bs + c * 16);
        }
        __syncthreads();
        #pragma unroll
        for (int kk = 0; kk < 64; kk += 32) {
            short8 a[4], b[4];
            int col = kk + (lane >> 4) * 8;
            #pragma unroll
            for (int mi = 0; mi < 4; mi++) {
                int row = wm * 64 + mi * 16 + (lane & 15);
                a[mi] = *(const short8*)&As[row * 64 + col];
            }
            #pragma unroll
            for (int ni = 0; ni < 4; ni++) {
                int row = wn * 64 + ni * 16 + (lane & 15);
                b[ni] = *(const short8*)&Bs[row * 64 + col];
            }
            #pragma unroll
            for (int mi = 0; mi < 4; mi++)
                #pragma unroll
                for (int ni = 0; ni < 4; ni++)
                    acc[mi][ni] = __builtin_amdgcn_mfma_f32_16x16x32_bf16(a[mi], b[ni], acc[mi][ni], 0, 0, 0);
        }
        __syncthreads();
    }

    int rq = lane >> 4, cl = lane & 15;
    #pragma unroll
    for (int mi = 0; mi < 4; mi++) {
        #pragma unroll
        for (int ni = 0; ni < 4; ni++) {
            int col = bx * 128 + wn * 64 + ni * 16 + cl;
            #pragma unroll
            for (int j = 0; j < 4; j++) {
                int row = by * 128 + wm * 64 + mi * 16 + rq * 4 + j;
                float v = acc[mi][ni][j];
                if (BIAS_EDGE) {
                    if (col < Nvalid) C[(size_t)row * ldc + col] = v + bias[col];
                } else {
                    C[(size_t)row * ldc + col] = v;
                }
            }
        }
    }
}

extern "C" void kernel_launch(void* const* d_in, const int* in_sizes, int n_in,
                              void* d_out, int out_size, void* d_ws, size_t ws_size,
                              hipStream_t stream) {
    const float* hidden = (const float*)d_in[0];
    const int*   span   = (const int*)d_in[1];
    const float* pe     = (const float*)d_in[2];
    const float* W1     = (const float*)d_in[3];
    const float* b1     = (const float*)d_in[4];
    const float* g1     = (const float*)d_in[5];
    const float* be1    = (const float*)d_in[6];
    const float* W2     = (const float*)d_in[7];
    const float* b2     = (const float*)d_in[8];
    const float* g2     = (const float*)d_in[9];
    const float* be2    = (const float*)d_in[10];
    const float* Wdec   = (const float*)d_in[11];
    const float* dbias  = (const float*)d_in[12];
    float* out = (float*)d_out;

    const int M = BSZ * SEQ;  // 2048
    char* ws = (char*)d_ws;
    size_t off = 0;
    int* fw = (int*)(ws + off);                 off += (size_t)M * 4;            // 8K
    int* bw = (int*)(ws + off);                 off += (size_t)M * 4;            // 8K
    __hip_bfloat16* Xb   = (__hip_bfloat16*)(ws + off); off += (size_t)M * 3 * HID * 2;     // 9.4M
    __hip_bfloat16* W1t  = (__hip_bfloat16*)(ws + off); off += (size_t)HID * 3 * HID * 2;   // 3.5M
    __hip_bfloat16* W2t  = (__hip_bfloat16*)(ws + off); off += (size_t)HID * HID * 2;       // 1.2M
    __hip_bfloat16* Wdt  = (__hip_bfloat16*)(ws + off); off += (size_t)NPAD * HID * 2;      // 47M
    float* Y             = (float*)(ws + off);          off += (size_t)M * HID * 4;         // 6.3M
    __hip_bfloat16* mid  = (__hip_bfloat16*)(ws + off); off += (size_t)M * HID * 2;         // 3.1M
    __hip_bfloat16* pre  = (__hip_bfloat16*)(ws + off); off += (size_t)M * HID * 2;         // 3.1M

    // 1. span scans
    scan_kernel<<<BSZ, SEQ, 0, stream>>>(span, fw, bw);
    // 2. gather + mask -> X bf16
    build_x<<<M, 256, 0, stream>>>(hidden, span, pe, fw, bw, Xb);
    // 3. weight transposes (f32 -> bf16, B^T layout)
    transpose_bf16<<<dim3(HID / 32, 3 * HID / 32), dim3(32, 8), 0, stream>>>(W1, W1t, 3 * HID, HID);
    transpose_bf16<<<dim3(HID / 32, HID / 32), dim3(32, 8), 0, stream>>>(W2, W2t, HID, HID);
    transpose_bf16<<<dim3(NPAD / 32, HID / 32), dim3(32, 8), 0, stream>>>(Wdec, Wdt, HID, VOC);
    // 4. GEMM1: X[2048,2304] @ W1 -> Y[2048,768]
    gemm_kernel<false><<<dim3(HID / 128, M / 128), 256, 0, stream>>>(Xb, W1t, Y, 3 * HID, 0, nullptr, HID);
    // 5. bias+gelu+LN -> mid bf16
    gelu_ln<<<M, 256, 0, stream>>>(Y, b1, g1, be1, mid);
    // 6. GEMM2: mid @ W2 -> Y
    gemm_kernel<false><<<dim3(HID / 128, M / 128), 256, 0, stream>>>(mid, W2t, Y, HID, 0, nullptr, HID);
    // 7. bias+gelu+LN -> pre bf16
    gelu_ln<<<M, 256, 0, stream>>>(Y, b2, g2, be2, pre);
    // 8. decoder GEMM: pre[2048,768] @ Wdec[768,30522] (+bias, edge-predicated)
    gemm_kernel<true><<<dim3(NPAD / 128, M / 128), 256, 0, stream>>>(pre, Wdt, out, HID, VOC, dbias, VOC);
}